// Round 1
// baseline (1762.114 us; speedup 1.0000x reference)
//
#include <hip/hip_runtime.h>
#include <hip/hip_bf16.h>
#include <cstdint>

#define NB 8192
#define TSTEPS 48

typedef __hip_bfloat16 bf16;
typedef short bf16x8 __attribute__((ext_vector_type(8)));
typedef float f32x4 __attribute__((ext_vector_type(4)));

__device__ __forceinline__ float sigf(float x) { return 1.0f / (1.0f + __expf(-x)); }
__device__ __forceinline__ float tanhf_fast(float x) { return 2.0f / (1.0f + __expf(-2.0f * x)) - 1.0f; }

// async global->LDS, 16B/lane. LDS dest = wave-uniform base + lane*16 (m104).
__device__ __forceinline__ void gld_lds16(const void* g, void* l) {
  typedef const __attribute__((address_space(1))) unsigned int* gp_t;
  typedef __attribute__((address_space(3))) unsigned int* lp_t;
  __builtin_amdgcn_global_load_lds(reinterpret_cast<gp_t>(reinterpret_cast<uintptr_t>(g)),
                                   reinterpret_cast<lp_t>(reinterpret_cast<uintptr_t>(l)),
                                   16, 0, 0);
}

// gate-interleaved packed gate-column order: p = (u>>4)*64 + g*16 + (u&15)
// -> one wave j-fragment = one gate; a thread's 4 j-frags = i,f,g,o of unit u.
__device__ __forceinline__ int orig_row_p(int p) {
  int ug = p >> 6, g = (p >> 4) & 3, s = p & 15;
  return g * 256 + ug * 16 + s;  // original row j = g*256 + u
}
// K-swizzle (T2 via pre-swizzled global, m173): original chunk c of row r stored at
// position c ^ ((r>>1)&3). unswz: which original k lands at stored col colp.
__device__ __forceinline__ int unswz_col(int colp, int r) {
  int cc = ((colp >> 3) & 3) ^ ((r >> 1) & 3);
  return (colp & ~31) | (cc << 3) | (colp & 7);
}

// ---------------- feats precompute: [T, N, 32] bf16 (swizzled chunks, cols 16..31 zero) ----
__global__ void feats_kernel(const float* __restrict__ x, const float* __restrict__ coords,
                             const float* __restrict__ env, const float* __restrict__ areas,
                             const float* __restrict__ bird, bf16* __restrict__ feats) {
  int idx = blockIdx.x * 256 + threadIdx.x;  // = t*NB + n
  int n = idx & (NB - 1);
  int t = idx >> 13;
  __align__(16) bf16 v[32];
  v[0] = __float2bfloat16(x[n * TSTEPS + t]);
  v[1] = __float2bfloat16(coords[n * 2 + 0]);
  v[2] = __float2bfloat16(coords[n * 2 + 1]);
#pragma unroll
  for (int e = 0; e < 10; ++e) v[3 + e] = __float2bfloat16(env[(n * 10 + e) * TSTEPS + t]);
  v[13] = __float2bfloat16(areas[n]);
  v[14] = __float2bfloat16(bird[(n * 2 + 0) * TSTEPS + t]);
  v[15] = __float2bfloat16(bird[(n * 2 + 1) * TSTEPS + t]);
#pragma unroll
  for (int f = 16; f < 32; ++f) v[f] = __float2bfloat16(0.0f);
  bf16* dst = feats + (size_t)idx * 32;
  int sw = (n >> 1) & 3;
#pragma unroll
  for (int c = 0; c < 4; ++c) ((bf16x8*)dst)[c ^ sw] = ((const bf16x8*)v)[c];
}

// ---------------- weight packing (gate-interleaved rows + K-chunk swizzle) ----------------
// WA: [1024, 288] = [W_hh0 (256) | Wc0 = W_ih0@W_in (16) | zeros (16)]
__global__ void packA_kernel(const float* __restrict__ W_hh0, const float* __restrict__ W_ih0,
                             const float* __restrict__ W_in, bf16* __restrict__ WA) {
  int idx = blockIdx.x * 256 + threadIdx.x;  // < 1024*288
  int p = idx / 288, colp = idx % 288;
  int j = orig_row_p(p);
  int k = unswz_col(colp, p);
  float val = 0.0f;
  if (k < 256) {
    val = W_hh0[j * 256 + k];
  } else if (k < 272) {
    int f = k - 256;
    float s = 0.0f;
    for (int kk = 0; kk < 256; ++kk) s += W_ih0[j * 256 + kk] * W_in[kk * 16 + f];
    val = s;
  }
  WA[(size_t)p * 288 + colp] = __float2bfloat16(val);
}

// WB: [1024, 512] = [W_ih1 (256) | W_hh1 (256)]
__global__ void packB_kernel(const float* __restrict__ W_ih1, const float* __restrict__ W_hh1,
                             bf16* __restrict__ WB) {
  int idx = blockIdx.x * 256 + threadIdx.x;  // < 1024*512
  int p = idx >> 9, colp = idx & 511;
  int j = orig_row_p(p);
  int k = unswz_col(colp, p);
  float val = (k < 256) ? W_ih1[j * 256 + k] : W_hh1[j * 256 + (k - 256)];
  WB[(size_t)p * 512 + colp] = __float2bfloat16(val);
}

// bias packed [gate][unit] (== original j = g*256+u, so identity reorder; just sum ih+hh)
__global__ void packBias_kernel(const float* __restrict__ b_ih, const float* __restrict__ b_hh,
                                float* __restrict__ bA, float* __restrict__ bB) {
  int idx = blockIdx.x * 256 + threadIdx.x;  // < 2048
  int layer = idx >> 10, r = idx & 1023;
  float v = b_ih[layer * 1024 + r] + b_hh[layer * 1024 + r];
  if (layer == 0) bA[r] = v; else bB[r] = v;
}

// ---------------- merged fused step: both layers' GEMMs + cells in ONE block ----------------
// Block = 128 rows x 256 packed gate-cols; 8 waves (2Mx4N), wave tile 64x64, dual acc.
// Single pipelined loop over nB(=16, layer1 @ tB) + nA(=9, layer0 @ tA) K-iters:
//   stage(it+1) -> ds_read frags(it) -> 16 MFMA -> __syncthreads (vmcnt drain = dbuf publish).
// Epilogue is register-local (gate-interleaved packing), no LDS roundtrip.
__global__ __launch_bounds__(512, 2) void lstm_step(
    const bf16* __restrict__ h0r, bf16* __restrict__ h0w,
    const bf16* __restrict__ h1r, bf16* __restrict__ h1w,
    const bf16* __restrict__ feats,
    const bf16* __restrict__ WA, const bf16* __restrict__ WB,
    const float* __restrict__ bA, const float* __restrict__ bB,
    bf16* __restrict__ c0, bf16* __restrict__ c1,
    float* __restrict__ out, int tA, int tB, int doA, int doB, int lastA, int lastB) {
  __shared__ __align__(16) bf16 As[2 * 128 * 32];
  __shared__ __align__(16) bf16 Bs[2 * 256 * 32];

  const int tid = threadIdx.x;
  const int wid = tid >> 6, lane = tid & 63;
  const int quad = lane >> 4, l16 = lane & 15;
  const int wr = wid >> 2, wc = wid & 3;

  // XCD-ownership swizzle: xcd = id%8 gets contiguous row-blocks (all q) -> h/c slices
  // stay XCD-L2-resident across all 48 steps; weights replicate (1.6 MB) per XCD.
  const int id = blockIdx.x;
  const int swz = (id & 7) * 32 + (id >> 3);
  const int rowbase = (swz >> 2) * 128;
  const int q = swz & 3;  // packed-col block [q*256, q*256+256)

  const int nB = doB ? 16 : 0;
  const int NT = nB + (doA ? 9 : 0);

  const int r4 = lane >> 2;
  const int ch = (lane & 3) * 8;                   // staging chunk (elements)
  const int cb = (quad ^ ((l16 >> 1) & 3)) * 8;    // swizzled read chunk: 2-way = free

  f32x4 accA[4][4], accB[4][4];
#pragma unroll
  for (int i = 0; i < 4; ++i)
#pragma unroll
    for (int j = 0; j < 4; ++j) {
      accA[i][j] = f32x4{0.f, 0.f, 0.f, 0.f};
      accB[i][j] = f32x4{0.f, 0.f, 0.f, 0.f};
    }

  auto stage = [&](int it, int buf) {
    // A-tile: 128 rows x 32 cols (8 KB, 1 KB/wave)
    const bf16* asrc; int astr;
    if (it < nB) {
      if (it < 8) { asrc = h0r + it * 32; astr = 256; }
      else        { asrc = h1r + (it - 8) * 32; astr = 256; }
    } else {
      int ka = it - nB;
      if (ka < 8) { asrc = h0r + ka * 32; astr = 256; }
      else        { asrc = feats + (size_t)tA * (NB * 32); astr = 32; }
    }
    const bf16* ga = asrc + (size_t)(rowbase + wid * 16 + r4) * astr + ch;
    gld_lds16(ga, As + buf * (128 * 32) + wid * (16 * 32));
    // B-tile (weights): 256 rows x 32 cols (16 KB, 2 KB/wave)
    const bf16* wsrc; int kw;
    if (it < nB) { wsrc = WB + it * 32; kw = 512; }
    else         { wsrc = WA + (it - nB) * 32; kw = 288; }
    const bf16* gb = wsrc + (size_t)(q * 256 + wid * 32 + r4) * kw + ch;
    bf16* lB = Bs + buf * (256 * 32) + wid * (32 * 32);
    gld_lds16(gb, lB);
    gld_lds16(gb + (size_t)16 * kw, lB + 16 * 32);
  };

  stage(0, 0);
  __syncthreads();

  for (int it = 0; it < NT; ++it) {
    const int buf = it & 1;
    if (it + 1 < NT) stage(it + 1, buf ^ 1);  // prefetch overlaps this iter's compute
    const bf16* Ab = As + buf * (128 * 32);
    const bf16* Bb = Bs + buf * (256 * 32);
    bf16x8 af[4], bfr[4];
#pragma unroll
    for (int i = 0; i < 4; ++i)
      af[i] = *(const bf16x8*)(Ab + (wr * 64 + i * 16 + l16) * 32 + cb);
#pragma unroll
    for (int j = 0; j < 4; ++j)
      bfr[j] = *(const bf16x8*)(Bb + (wc * 64 + j * 16 + l16) * 32 + cb);
    if (it < nB) {
#pragma unroll
      for (int i = 0; i < 4; ++i)
#pragma unroll
        for (int j = 0; j < 4; ++j)
          accB[i][j] = __builtin_amdgcn_mfma_f32_16x16x32_bf16(af[i], bfr[j], accB[i][j], 0, 0, 0);
    } else {
#pragma unroll
      for (int i = 0; i < 4; ++i)
#pragma unroll
        for (int j = 0; j < 4; ++j)
          accA[i][j] = __builtin_amdgcn_mfma_f32_16x16x32_bf16(af[i], bfr[j], accA[i][j], 0, 0, 0);
    }
    __syncthreads();  // vmcnt(0)+lgkmcnt(0)+barrier: publishes next buf, retires reads
  }

  // register-local epilogue: thread's 4 j-frags are i,f,g,o of unit u (gate-interleave)
  const int u = (q * 4 + wc) * 16 + l16;
  auto cell = [&](f32x4 (&acc)[4][4], const float* __restrict__ bias, bf16* __restrict__ cst,
                  bf16* __restrict__ hout, int last, float* __restrict__ oh,
                  float* __restrict__ oc) {
    const float bi = bias[u], bf_ = bias[256 + u], bg = bias[512 + u], bo = bias[768 + u];
#pragma unroll
    for (int i = 0; i < 4; ++i) {
#pragma unroll
      for (int rr = 0; rr < 4; ++rr) {
        const int n = rowbase + wr * 64 + i * 16 + quad * 4 + rr;
        const size_t ci = (size_t)n * 256 + u;
        float gi = sigf(acc[i][0][rr] + bi);
        float gf = sigf(acc[i][1][rr] + bf_);
        float gg = tanhf_fast(acc[i][2][rr] + bg);
        float go = sigf(acc[i][3][rr] + bo);
        float c = __bfloat162float(cst[ci]);
        float cn = gf * c + gi * gg;
        float hn = go * tanhf_fast(cn);
        if (!last) cst[ci] = __float2bfloat16(cn);
        // h stored K-swizzled so next step's staging reads it conflict-free
        const int col = (u & ~31) | (((((u >> 3) & 3) ^ ((n >> 1) & 3))) << 3) | (u & 7);
        hout[(size_t)n * 256 + col] = __float2bfloat16(hn);
        if (last) { oh[ci] = hn; oc[ci] = cn; }
      }
    }
  };
  if (doB) cell(accB, bB, c1, h1w, lastB, out + (size_t)NB * 256, out + (size_t)3 * NB * 256);
  if (doA) cell(accA, bA, c0, h0w, lastA, out, out + (size_t)2 * NB * 256);
}

extern "C" void kernel_launch(void* const* d_in, const int* in_sizes, int n_in,
                              void* d_out, int out_size, void* d_ws, size_t ws_size,
                              hipStream_t stream) {
  const float* x = (const float*)d_in[0];
  const float* coords = (const float*)d_in[1];
  const float* env = (const float*)d_in[2];
  const float* areas = (const float*)d_in[3];
  const float* bird = (const float*)d_in[4];
  const float* W_in = (const float*)d_in[5];
  const float* W_ih = (const float*)d_in[6];  // [2,1024,256]
  const float* W_hh = (const float*)d_in[7];  // [2,1024,256]
  const float* b_ih = (const float*)d_in[8];  // [2,1024]
  const float* b_hh = (const float*)d_in[9];  // [2,1024]
  float* out = (float*)d_out;

  const size_t MB = 1 << 20;
  char* w0 = (char*)d_ws;
  // layout: [H0_0 4][H1_0 4][H0_1 4][H1_1 4][c0 4][c1 4][feats 24][WA][WB][bA][bB] (MB)
  auto H0 = [&](int i) { return (bf16*)(w0 + (size_t)i * 8 * MB); };
  auto H1 = [&](int i) { return (bf16*)(w0 + 4 * MB + (size_t)i * 8 * MB); };
  bf16* c0 = (bf16*)(w0 + 16 * MB);
  bf16* c1 = (bf16*)(w0 + 20 * MB);
  bf16* feats = (bf16*)(w0 + 24 * MB);
  bf16* WA = (bf16*)(w0 + 48 * MB);
  bf16* WB = (bf16*)(w0 + 49 * MB);
  float* bA = (float*)(w0 + 50 * MB);
  float* bB = (float*)(w0 + 50 * MB + 4096);

  // zero H0(1), H1(1) (initial states) and c0, c1 — contiguous [8MB, 24MB)
  hipMemsetAsync(w0 + 8 * MB, 0, 16 * MB, stream);

  feats_kernel<<<(NB * TSTEPS) / 256, 256, 0, stream>>>(x, coords, env, areas, bird, feats);
  packA_kernel<<<(1024 * 288) / 256, 256, 0, stream>>>(W_hh, W_ih, W_in, WA);
  packB_kernel<<<(1024 * 512) / 256, 256, 0, stream>>>(W_ih + 1024 * 256, W_hh + 1024 * 256, WB);
  packBias_kernel<<<2048 / 256, 256, 0, stream>>>(b_ih, b_hh, bA, bB);

  // h0(t) lives in H0(t&1); h1(t) in H1(t&1).
  // launch s: A = layer0 @ t=s (reads h0(s-1), feats(s); writes h0(s))
  //           B = layer1 @ t=s-1 (reads h0(s-1), h1(s-2); writes h1(s-1))
  for (int s = 0; s <= 48; ++s) {
    lstm_step<<<dim3(256), 512, 0, stream>>>(
        H0((s + 1) & 1), H0(s & 1), H1(s & 1), H1((s + 1) & 1),
        feats, WA, WB, bA, bB, c0, c1, out,
        /*tA*/s, /*tB*/s - 1,
        /*doA*/(s <= 47) ? 1 : 0, /*doB*/(s >= 1) ? 1 : 0,
        /*lastA*/(s == 47) ? 1 : 0, /*lastB*/(s == 48) ? 1 : 0);
  }
}

// Round 2
// 1375.861 us; speedup vs baseline: 1.2807x; 1.2807x over previous
//
#include <hip/hip_runtime.h>
#include <hip/hip_bf16.h>
#include <cstdint>

#define NB 8192
#define TSTEPS 48

typedef __hip_bfloat16 bf16;
typedef short bf16x8 __attribute__((ext_vector_type(8)));
typedef float f32x4 __attribute__((ext_vector_type(4)));

__device__ __forceinline__ float sigf(float x) { return 1.0f / (1.0f + __expf(-x)); }
__device__ __forceinline__ float tanhf_fast(float x) { return 2.0f / (1.0f + __expf(-2.0f * x)) - 1.0f; }

// async global->LDS, 16B/lane. LDS dest = wave-uniform base + lane*16 (m104).
__device__ __forceinline__ void gld_lds16(const void* g, void* l) {
  typedef const __attribute__((address_space(1))) unsigned int* gp_t;
  typedef __attribute__((address_space(3))) unsigned int* lp_t;
  __builtin_amdgcn_global_load_lds(reinterpret_cast<gp_t>(reinterpret_cast<uintptr_t>(g)),
                                   reinterpret_cast<lp_t>(reinterpret_cast<uintptr_t>(l)),
                                   16, 0, 0);
}

// gate-interleaved packed gate-column order: p = (u>>4)*64 + g*16 + (u&15)
// -> one wave j-fragment = one gate; a thread's 4 j-frags = i,f,g,o of unit u.
__device__ __forceinline__ int orig_row_p(int p) {
  int ug = p >> 6, g = (p >> 4) & 3, s = p & 15;
  return g * 256 + ug * 16 + s;  // original row j = g*256 + u
}
// K-swizzle (T2 via pre-swizzled global, m173): original chunk c of row r stored at
// position c ^ ((r>>1)&3). unswz: which original k lands at stored col colp.
__device__ __forceinline__ int unswz_col(int colp, int r) {
  int cc = ((colp >> 3) & 3) ^ ((r >> 1) & 3);
  return (colp & ~31) | (cc << 3) | (colp & 7);
}

// ---------------- feats precompute: [T, N, 32] bf16 (swizzled chunks, cols 16..31 zero) ----
__global__ void feats_kernel(const float* __restrict__ x, const float* __restrict__ coords,
                             const float* __restrict__ env, const float* __restrict__ areas,
                             const float* __restrict__ bird, bf16* __restrict__ feats) {
  int idx = blockIdx.x * 256 + threadIdx.x;  // = t*NB + n
  int n = idx & (NB - 1);
  int t = idx >> 13;
  __align__(16) bf16 v[32];
  v[0] = __float2bfloat16(x[n * TSTEPS + t]);
  v[1] = __float2bfloat16(coords[n * 2 + 0]);
  v[2] = __float2bfloat16(coords[n * 2 + 1]);
#pragma unroll
  for (int e = 0; e < 10; ++e) v[3 + e] = __float2bfloat16(env[(n * 10 + e) * TSTEPS + t]);
  v[13] = __float2bfloat16(areas[n]);
  v[14] = __float2bfloat16(bird[(n * 2 + 0) * TSTEPS + t]);
  v[15] = __float2bfloat16(bird[(n * 2 + 1) * TSTEPS + t]);
#pragma unroll
  for (int f = 16; f < 32; ++f) v[f] = __float2bfloat16(0.0f);
  bf16* dst = feats + (size_t)idx * 32;
  int sw = (n >> 1) & 3;
#pragma unroll
  for (int c = 0; c < 4; ++c) ((bf16x8*)dst)[c ^ sw] = ((const bf16x8*)v)[c];
}

// ---------------- weight packing (gate-interleaved rows + K-chunk swizzle) ----------------
// WA: [1024, 288] = [W_hh0 (256) | Wc0 = W_ih0@W_in (16) | zeros (16)]
__global__ void packA_kernel(const float* __restrict__ W_hh0, const float* __restrict__ W_ih0,
                             const float* __restrict__ W_in, bf16* __restrict__ WA) {
  int idx = blockIdx.x * 256 + threadIdx.x;  // < 1024*288
  int p = idx / 288, colp = idx % 288;
  int j = orig_row_p(p);
  int k = unswz_col(colp, p);
  float val = 0.0f;
  if (k < 256) {
    val = W_hh0[j * 256 + k];
  } else if (k < 272) {
    int f = k - 256;
    float s = 0.0f;
    for (int kk = 0; kk < 256; ++kk) s += W_ih0[j * 256 + kk] * W_in[kk * 16 + f];
    val = s;
  }
  WA[(size_t)p * 288 + colp] = __float2bfloat16(val);
}

// WB: [1024, 512] = [W_ih1 (256) | W_hh1 (256)]
__global__ void packB_kernel(const float* __restrict__ W_ih1, const float* __restrict__ W_hh1,
                             bf16* __restrict__ WB) {
  int idx = blockIdx.x * 256 + threadIdx.x;  // < 1024*512
  int p = idx >> 9, colp = idx & 511;
  int j = orig_row_p(p);
  int k = unswz_col(colp, p);
  float val = (k < 256) ? W_ih1[j * 256 + k] : W_hh1[j * 256 + (k - 256)];
  WB[(size_t)p * 512 + colp] = __float2bfloat16(val);
}

// bias packed [gate][unit] (== original j = g*256+u, identity reorder; sum ih+hh)
__global__ void packBias_kernel(const float* __restrict__ b_ih, const float* __restrict__ b_hh,
                                float* __restrict__ bA, float* __restrict__ bB) {
  int idx = blockIdx.x * 256 + threadIdx.x;  // < 2048
  int layer = idx >> 10, r = idx & 1023;
  float v = b_ih[layer * 1024 + r] + b_hh[layer * 1024 + r];
  if (layer == 0) bA[r] = v; else bB[r] = v;
}

// ---------------- fused GEMM + LSTM cell step ----------------
// R2: proven R0 geometry (grid 64x8x2, 256 thr, 128x128 tile, 4 blk/CU — the TLP that
// hides the barrier drain, m114) + two R1-verified deltas that don't touch occupancy:
//   (a) double-buffered staging, ONE barrier/iter (was 2): stage(k+1) overlaps compute(k)
//   (b) register-local epilogue via gate-interleaved packing: Gs roundtrip + 4 barriers gone
// phase = blockIdx.z + phase0: 0 = layer-1 at tB (B), 1 = layer-0 at tA (A).
__global__ __launch_bounds__(256, 4) void lstm_step(
    const bf16* __restrict__ h0r, bf16* __restrict__ h0w,
    const bf16* __restrict__ h1r, bf16* __restrict__ h1w,
    const bf16* __restrict__ feats,
    const bf16* __restrict__ WA, const bf16* __restrict__ WB,
    const float* __restrict__ bA, const float* __restrict__ bB,
    bf16* __restrict__ c0, bf16* __restrict__ c1,
    float* __restrict__ out, int tA, int tB, int phase0, int lastA, int lastB) {
  __shared__ __align__(16) bf16 As[2 * 128 * 32];
  __shared__ __align__(16) bf16 Bs[2 * 128 * 32];

  const int tid = threadIdx.x;
  const int wid = tid >> 6, lane = tid & 63;
  const int quad = lane >> 4, l16 = lane & 15;
  const int mb = (wid >> 1) * 64, nb = (wid & 1) * 64;
  const int rowbase = blockIdx.x * 128;
  const int q = blockIdx.y;
  const int isA = blockIdx.z + phase0;  // 0 = B, 1 = A

  const bf16* Wp = isA ? WA : WB;
  const int KW = isA ? 288 : 512;
  const int KITERS = isA ? 9 : 16;

  f32x4 acc[4][4];
#pragma unroll
  for (int i = 0; i < 4; ++i)
#pragma unroll
    for (int j = 0; j < 4; ++j) acc[i][j] = f32x4{0.f, 0.f, 0.f, 0.f};

  const int r4 = lane >> 2;                      // 0..15
  const int ch = (lane & 3) * 8;                 // staging chunk (elements) — linear
  const int cb = (quad ^ ((l16 >> 1) & 3)) * 8;  // swizzled read chunk (conflict-free)
  const int arow = wid * 32 + r4;                // staging row within 128-tile
  const bf16* WGrow = Wp + (size_t)(q * 128 + arow) * KW + ch;

  auto stage = [&](int kb, int buf) {
    const bf16* asrc;
    int astr;
    if (isA && kb == 8) {
      asrc = feats + (size_t)tA * (NB * 32);
      astr = 32;
    } else if (!isA && kb >= 8) {
      asrc = h1r + (kb - 8) * 32;
      astr = 256;
    } else {
      asrc = h0r + kb * 32;
      astr = 256;
    }
    const bf16* ga = asrc + (size_t)(rowbase + arow) * astr + ch;
    bf16* lA = As + buf * (128 * 32) + wid * (32 * 32);
    gld_lds16(ga, lA);
    gld_lds16(ga + (size_t)16 * astr, lA + 16 * 32);
    const bf16* gb = WGrow + kb * 32;
    bf16* lB = Bs + buf * (128 * 32) + wid * (32 * 32);
    gld_lds16(gb, lB);
    gld_lds16(gb + (size_t)16 * KW, lB + 16 * 32);
  };

  stage(0, 0);
  __syncthreads();  // vmcnt drain publishes buf 0

  for (int kb = 0; kb < KITERS; ++kb) {
    const int buf = kb & 1;
    if (kb + 1 < KITERS) stage(kb + 1, buf ^ 1);  // prefetch overlaps this iter's compute
    const bf16* Ab = As + buf * (128 * 32);
    const bf16* Bb = Bs + buf * (128 * 32);
    bf16x8 af[4], bfr[4];
#pragma unroll
    for (int i = 0; i < 4; ++i) af[i] = *(const bf16x8*)(Ab + (mb + i * 16 + l16) * 32 + cb);
#pragma unroll
    for (int j = 0; j < 4; ++j) bfr[j] = *(const bf16x8*)(Bb + (nb + j * 16 + l16) * 32 + cb);
#pragma unroll
    for (int i = 0; i < 4; ++i)
#pragma unroll
      for (int j = 0; j < 4; ++j)
        acc[i][j] = __builtin_amdgcn_mfma_f32_16x16x32_bf16(af[i], bfr[j], acc[i][j], 0, 0, 0);
    if (kb + 1 < KITERS) __syncthreads();  // publishes buf^1, retires this buf's reads
  }

  // register-local epilogue: wave j-frag = gate j of unit u (gate-interleaved packing)
  const int u = (q * 2 + (nb >> 6)) * 16 + l16;
  const float* bias = isA ? bA : bB;
  bf16* cst = isA ? c0 : c1;
  bf16* hout = isA ? h0w : h1w;
  const int last = isA ? lastA : lastB;
  float* out_h = out + (size_t)(isA ? 0 : 1) * NB * 256;
  float* out_c = out + (size_t)(isA ? 2 : 3) * NB * 256;
  const float bi = bias[u], bf_ = bias[256 + u], bg = bias[512 + u], bo = bias[768 + u];
#pragma unroll
  for (int i = 0; i < 4; ++i) {
#pragma unroll
    for (int rr = 0; rr < 4; ++rr) {
      const int n = rowbase + mb + i * 16 + quad * 4 + rr;
      const size_t ci = (size_t)n * 256 + u;
      float gi = sigf(acc[i][0][rr] + bi);
      float gf = sigf(acc[i][1][rr] + bf_);
      float gg = tanhf_fast(acc[i][2][rr] + bg);
      float go = sigf(acc[i][3][rr] + bo);
      float c = __bfloat162float(cst[ci]);
      float cn = gf * c + gi * gg;
      float hn = go * tanhf_fast(cn);
      if (!last) cst[ci] = __float2bfloat16(cn);
      // h stored K-swizzled so next step's staging reads it conflict-free
      const int col = (u & ~31) | ((((u >> 3) & 3) ^ ((n >> 1) & 3)) << 3) | (u & 7);
      hout[(size_t)n * 256 + col] = __float2bfloat16(hn);
      if (last) { out_h[ci] = hn; out_c[ci] = cn; }
    }
  }
}

extern "C" void kernel_launch(void* const* d_in, const int* in_sizes, int n_in,
                              void* d_out, int out_size, void* d_ws, size_t ws_size,
                              hipStream_t stream) {
  const float* x = (const float*)d_in[0];
  const float* coords = (const float*)d_in[1];
  const float* env = (const float*)d_in[2];
  const float* areas = (const float*)d_in[3];
  const float* bird = (const float*)d_in[4];
  const float* W_in = (const float*)d_in[5];
  const float* W_ih = (const float*)d_in[6];  // [2,1024,256]
  const float* W_hh = (const float*)d_in[7];  // [2,1024,256]
  const float* b_ih = (const float*)d_in[8];  // [2,1024]
  const float* b_hh = (const float*)d_in[9];  // [2,1024]
  float* out = (float*)d_out;

  const size_t MB = 1 << 20;
  char* w0 = (char*)d_ws;
  // layout: [H0_0 4][H1_0 4][H0_1 4][H1_1 4][c0 4][c1 4][feats 24][WA][WB][bA][bB] (MB)
  auto H0 = [&](int i) { return (bf16*)(w0 + (size_t)i * 8 * MB); };
  auto H1 = [&](int i) { return (bf16*)(w0 + 4 * MB + (size_t)i * 8 * MB); };
  bf16* c0 = (bf16*)(w0 + 16 * MB);
  bf16* c1 = (bf16*)(w0 + 20 * MB);
  bf16* feats = (bf16*)(w0 + 24 * MB);
  bf16* WA = (bf16*)(w0 + 48 * MB);
  bf16* WB = (bf16*)(w0 + 49 * MB);
  float* bA = (float*)(w0 + 50 * MB);
  float* bB = (float*)(w0 + 50 * MB + 4096);

  // zero H0(1), H1(1) (initial state) and c0, c1 — contiguous [8MB, 24MB)
  hipMemsetAsync(w0 + 8 * MB, 0, 16 * MB, stream);

  feats_kernel<<<(NB * TSTEPS) / 256, 256, 0, stream>>>(x, coords, env, areas, bird, feats);
  packA_kernel<<<(1024 * 288) / 256, 256, 0, stream>>>(W_hh, W_ih, W_in, WA);
  packB_kernel<<<(1024 * 512) / 256, 256, 0, stream>>>(W_ih + 1024 * 256, W_hh + 1024 * 256, WB);
  packBias_kernel<<<2048 / 256, 256, 0, stream>>>(b_ih, b_hh, bA, bB);

  // A(0): reads H0(1) (zero), writes H0(0)
  lstm_step<<<dim3(64, 8, 1), 256, 0, stream>>>(
      H0(1), H0(0), H1(0), H1(1), feats, WA, WB, bA, bB, c0, c1, out,
      /*tA*/0, /*tB*/0, /*phase0*/1, /*lastA*/0, /*lastB*/0);
  // combined: z=0 -> B(s2), z=1 -> A(s2+1). Both read h0(s2)=H0(s2&1).
  for (int s2 = 0; s2 <= 46; ++s2) {
    int pa = (s2 + 1) & 1, pb = s2 & 1;
    lstm_step<<<dim3(64, 8, 2), 256, 0, stream>>>(
        H0(pb), H0(pa), H1(pa), H1(pb), feats, WA, WB, bA, bB, c0, c1, out,
        /*tA*/s2 + 1, /*tB*/s2, /*phase0*/0, /*lastA*/(s2 == 46), /*lastB*/0);
  }
  // B(47): reads H0(1), H1(0); writes H1(1)
  lstm_step<<<dim3(64, 8, 1), 256, 0, stream>>>(
      H0(1), H0(0), H1(0), H1(1), feats, WA, WB, bA, bB, c0, c1, out,
      /*tA*/0, /*tB*/47, /*phase0*/0, /*lastA*/0, /*lastB*/1);
}